// Round 1
// baseline (689.156 us; speedup 1.0000x reference)
//
#include <hip/hip_runtime.h>

namespace {

constexpr int B = 8, C = 19, H = 512, W = 512;
constexpr int OH = 502, OW = 502;          // VALID conv output
constexpr int HW = H * W;
constexpr int TH = 32, TW = 64;            // output tile per block
constexpr int IH = TH + 10, IW = TW + 10;  // input tile (42 x 74)

// Gaussian g (win=11, sigma=1.5), normalized. Symmetric.
__device__ constexpr float G[11] = {
    0.00102838f, 0.00759876f, 0.03600077f, 0.10936070f, 0.21300553f,
    0.26601173f,
    0.21300553f, 0.10936070f, 0.03600077f, 0.00759876f, 0.00102838f};

// ---------------------------------------------------------------------------
// K1: softmax denominator (reciprocal) + target compaction + accum zeroing
// ---------------------------------------------------------------------------
__global__ __launch_bounds__(256) void denom_kernel(
    const float* __restrict__ pred, const int* __restrict__ target,
    float* __restrict__ rs, unsigned char* __restrict__ t8,
    float* __restrict__ accum) {
  int idx = blockIdx.x * 256 + threadIdx.x;  // pixel index in [0, B*HW)
  if (blockIdx.x == 0 && threadIdx.x < B * C) accum[threadIdx.x] = 0.0f;
  if (idx >= B * HW) return;
  int b = idx / HW;
  int px = idx - b * HW;
  const float* pp = pred + (size_t)b * C * HW + px;
  float s = 0.0f;
#pragma unroll
  for (int c = 0; c < C; ++c) s += __expf(pp[c * HW]);
  rs[idx] = 1.0f / s;
  t8[idx] = (unsigned char)target[idx];
}

// ---------------------------------------------------------------------------
// K2: fused softmax + 4-field separable 11x11 conv + SSIM + partial reduce
// ---------------------------------------------------------------------------
__global__ __launch_bounds__(256) void ssim_kernel(
    const float* __restrict__ pred, const float* __restrict__ rs,
    const unsigned char* __restrict__ t8, float* __restrict__ accum) {
  __shared__ float sRS[IH][IW];          // 12432 B
  __shared__ unsigned char sT[IH][IW];   // 3108 B
  __shared__ float sP[IH][IW];           // 12432 B
  __shared__ float sH[4][IH][TW];        // 43008 B  (hp, hp2, hpt, ht)
  __shared__ float red[4];

  const int x0 = blockIdx.x * TW;
  const int y0 = blockIdx.y * TH;
  const int b = blockIdx.z;
  const int ow = min(TW, OW - x0);
  const int oh = min(TH, OH - y0);
  const int iw = ow + 10;
  const int ih = oh + 10;
  const int tid = threadIdx.x;

  // stage 1/s and target tiles (once per block)
  for (int i = tid; i < ih * iw; i += 256) {
    int r = i / iw, col = i - r * iw;
    int g = b * HW + (y0 + r) * W + (x0 + col);
    sRS[r][col] = rs[g];
    sT[r][col] = t8[g];
  }
  __syncthreads();

  for (int c = 0; c < C; ++c) {
    // stage p = exp(x) * (1/sum exp) for this channel
    const float* pc = pred + (size_t)(b * C + c) * HW;
    for (int i = tid; i < ih * iw; i += 256) {
      int r = i / iw, col = i - r * iw;
      sP[r][col] = __expf(pc[(y0 + r) * W + (x0 + col)]) * sRS[r][col];
    }
    __syncthreads();

    // horizontal 11-tap conv of the 4 fields
    for (int i = tid; i < ih * TW; i += 256) {
      int r = i >> 6;
      int col = i & 63;
      if (col < ow) {
        float hp = 0.f, hp2 = 0.f, hpt = 0.f, ht = 0.f;
#pragma unroll
        for (int j = 0; j < 11; ++j) {
          float v = sP[r][col + j];
          float tf = (sT[r][col + j] == (unsigned char)c) ? 1.0f : 0.0f;
          float gj = G[j];
          hp += gj * v;
          hp2 += gj * v * v;
          hpt += gj * v * tf;
          ht += gj * tf;
        }
        sH[0][r][col] = hp;
        sH[1][r][col] = hp2;
        sH[2][r][col] = hpt;
        sH[3][r][col] = ht;
      }
    }
    __syncthreads();

    // vertical 11-tap conv + SSIM math, accumulate per-thread
    float acc = 0.0f;
    for (int i = tid; i < TH * TW; i += 256) {
      int r = i >> 6;
      int col = i & 63;
      if (r < oh && col < ow) {
        float mu1 = 0.f, dp2 = 0.f, dpt = 0.f, mu2 = 0.f;
#pragma unroll
        for (int j = 0; j < 11; ++j) {
          float gj = G[j];
          mu1 += gj * sH[0][r + j][col];
          dp2 += gj * sH[1][r + j][col];
          dpt += gj * sH[2][r + j][col];
          mu2 += gj * sH[3][r + j][col];
        }
        float mu12 = mu1 * mu2;
        float var1 = dp2 - mu1 * mu1;
        float var2 = mu2 - mu2 * mu2;       // t^2 == t (one-hot)
        float covar = dpt - mu12;
        const float c1 = 1e-4f, c2 = 9e-4f;
        float cs = (2.0f * covar + c2) / (var1 + var2 + c2);
        float ssv = (2.0f * mu12 + c1) / (mu1 * mu1 + mu2 * mu2 + c1) * cs;
        acc += ssv;
      }
    }

    // block reduce + one atomic per (block, channel)
    for (int off = 32; off > 0; off >>= 1) acc += __shfl_down(acc, off);
    if ((tid & 63) == 0) red[tid >> 6] = acc;
    __syncthreads();
    if (tid == 0)
      atomicAdd(&accum[b * C + c], red[0] + red[1] + red[2] + red[3]);
    // next channel's sP/sH writes are fenced by the staging/horizontal
    // __syncthreads() above; red[] reuse is fenced the same way.
  }
}

// ---------------------------------------------------------------------------
// K3: final reduction: per-(b,c) mean, relu, 1 - mean
// ---------------------------------------------------------------------------
__global__ __launch_bounds__(256) void finish_kernel(
    const float* __restrict__ accum, float* __restrict__ out) {
  __shared__ float red[4];
  int tid = threadIdx.x;
  float v = 0.0f;
  if (tid < B * C) {
    float m = accum[tid] * (1.0f / (float)(OH * OW));
    v = m > 0.0f ? m : 0.0f;
  }
  for (int off = 32; off > 0; off >>= 1) v += __shfl_down(v, off);
  if ((tid & 63) == 0) red[tid >> 6] = v;
  __syncthreads();
  if (tid == 0) out[0] = 1.0f - (red[0] + red[1] + red[2] + red[3]) /
                                    (float)(B * C);
}

}  // namespace

extern "C" void kernel_launch(void* const* d_in, const int* in_sizes, int n_in,
                              void* d_out, int out_size, void* d_ws,
                              size_t ws_size, hipStream_t stream) {
  const float* pred = (const float*)d_in[0];
  const int* target = (const int*)d_in[1];
  float* out = (float*)d_out;

  // workspace layout: rs (B*HW f32) | t8 (B*HW u8) | accum (B*C f32)
  float* rs = (float*)d_ws;
  unsigned char* t8 = (unsigned char*)d_ws + (size_t)B * HW * sizeof(float);
  float* accum = (float*)((char*)d_ws + (size_t)B * HW * 5);

  denom_kernel<<<(B * HW + 255) / 256, 256, 0, stream>>>(pred, target, rs, t8,
                                                         accum);
  dim3 grid((OW + TW - 1) / TW, (OH + TH - 1) / TH, B);
  ssim_kernel<<<grid, 256, 0, stream>>>(pred, rs, t8, accum);
  finish_kernel<<<1, 256, 0, stream>>>(accum, out);
}